// Round 15
// baseline (157.420 us; speedup 1.0000x reference)
//
#include <hip/hip_runtime.h>
#include <math.h>

#define NB   8
#define HH   64
#define NC   128
#define NHID 512
#define NL   4096

typedef __attribute__((ext_vector_type(4))) float f32x4;
typedef __attribute__((ext_vector_type(8))) __bf16 bf16x8;

__device__ __forceinline__ float gelu_f(float v) {
  return 0.5f * v * (1.f + erff(v * 0.70710678118654752f));
}
__device__ __forceinline__ float sigmoid_f(float v) {
  return 1.f / (1.f + expf(-v));
}
__device__ __forceinline__ unsigned short f2bf(float f) {
  unsigned int u = __builtin_bit_cast(unsigned int, f);
  unsigned int r = (u + 0x7FFFu + ((u >> 16) & 1u)) >> 16;
  return (unsigned short)r;
}
__device__ __forceinline__ float bf2f(unsigned short h) {
  return __builtin_bit_cast(float, ((unsigned int)h) << 16);
}
__device__ __forceinline__ float bflo(unsigned int w) {
  return __builtin_bit_cast(float, w << 16);
}
__device__ __forceinline__ float bfhi(unsigned int w) {
  return __builtin_bit_cast(float, w & 0xFFFF0000u);
}
__device__ __forceinline__ void gld16(const void* g, void* l) {
  __builtin_amdgcn_global_load_lds(
      (const __attribute__((address_space(1))) unsigned int*)g,
      (__attribute__((address_space(3))) unsigned int*)l, 16, 0, 0);
}

__device__ __forceinline__ void bf16x8_store(const float4& a, const float4& b, void* dst) {
  unsigned int p0 = (unsigned int)f2bf(a.x) | ((unsigned int)f2bf(a.y) << 16);
  unsigned int p1 = (unsigned int)f2bf(a.z) | ((unsigned int)f2bf(a.w) << 16);
  unsigned int p2 = (unsigned int)f2bf(b.x) | ((unsigned int)f2bf(b.y) << 16);
  unsigned int p3 = (unsigned int)f2bf(b.z) | ((unsigned int)f2bf(b.w) << 16);
  *(uint4*)dst = make_uint4(p0, p1, p2, p3);
}

// ---------------- head: ln (0..8191) | prep_misc (8192..8346) | prep_ct (8347..8602) ----------------
__global__ __launch_bounds__(256) void head_kernel(const float* __restrict__ x,
    const float* __restrict__ ln1_g, const float* __restrict__ ln1_b,
    unsigned short* __restrict__ xln,
    const float* __restrict__ lin1_w, const float* __restrict__ lin2_w,
    const float* __restrict__ w_gk, const float* __restrict__ w_fus,
    const float* __restrict__ dw_w, const float* __restrict__ conv1_w,
    unsigned short* __restrict__ w1o, unsigned short* __restrict__ w2o,
    unsigned short* __restrict__ wgko, unsigned short* __restrict__ wf1o,
    unsigned short* __restrict__ wf2o, float* __restrict__ dwt,
    float* __restrict__ sfus,
    unsigned short* __restrict__ ctp, unsigned short* __restrict__ ctq) {
  int gblk = blockIdx.x, tid = threadIdx.x;
  if (gblk < 8192) {
    int wv = tid >> 6, l = tid & 63;
    int row = gblk * 4 + wv;
    const float2 v = *(const float2*)(x + (size_t)row * NC + l * 2);
    float s = v.x + v.y, ss = v.x * v.x + v.y * v.y;
#pragma unroll
    for (int off = 32; off > 0; off >>= 1) {
      s  += __shfl_down(s, off);
      ss += __shfl_down(ss, off);
    }
    s = __shfl(s, 0); ss = __shfl(ss, 0);
    float mean = s * (1.f / NC);
    float rstd = rsqrtf(ss * (1.f / NC) - mean * mean + 1e-5f);
    const float2 gg = *(const float2*)(ln1_g + l * 2);
    const float2 bv = *(const float2*)(ln1_b + l * 2);
    float o0 = (v.x - mean) * rstd * gg.x + bv.x;
    float o1 = (v.y - mean) * rstd * gg.y + bv.y;
    unsigned int pk = (unsigned int)f2bf(o0) | ((unsigned int)f2bf(o1) << 16);
    *(unsigned int*)((char*)xln + (size_t)row * 256 + ((l >> 2) << 4) + (l & 3) * 4) = pk;
    return;
  }
  if (gblk < 8347) {
    int blk = gblk - 8192;
    if (blk < 32) {                           // w1
      int idx = blk * 256 + tid;
      int n = idx >> 4, c16 = idx & 15;
      const float4 a = *(const float4*)(lin1_w + (size_t)n * 128 + c16 * 8);
      const float4 b = *(const float4*)(lin1_w + (size_t)n * 128 + c16 * 8 + 4);
      bf16x8_store(a, b, (char*)w1o + (size_t)n * 256 + ((c16 ^ (n & 7)) << 4));
    } else if (blk < 64) {                    // w2 blocked by kt
      int idx = (blk - 32) * 256 + tid;
      int kt = idx >> 11, c = (idx >> 4) & 127, c16 = idx & 15;
      const float* s = lin2_w + (size_t)c * NHID + kt * 128 + c16 * 8;
      const float4 a = *(const float4*)(s);
      const float4 b = *(const float4*)(s + 4);
      bf16x8_store(a, b, (char*)w2o + (size_t)(kt * 128 + c) * 256 + ((c16 ^ (c & 7)) << 4));
    } else if (blk < 96) {                    // wgk
      int idx = (blk - 64) * 256 + tid;
      int row = idx >> 4, c16 = idx & 15;
      int w = row >> 7, q = row & 127;
      const float* s = w_gk + (size_t)q * 512 + w * 128 + c16 * 8;
      const float4 a = *(const float4*)(s);
      const float4 b = *(const float4*)(s + 4);
      bf16x8_store(a, b, (char*)wgko + (size_t)row * 256 + ((c16 ^ (row & 7)) << 4));
    } else if (blk < 136) {                   // wf1 + wf2
      int idx = (blk - 96) * 256 + tid;
      if (idx < 8192) {
        int row = idx >> 4, c16 = idx & 15;
        int w = row >> 7, o = row & 127;
        const float* s = w_fus + (size_t)o * 640 + w * 128 + c16 * 8;
        const float4 a = *(const float4*)(s);
        const float4 b = *(const float4*)(s + 4);
        bf16x8_store(a, b, (char*)wf1o + (size_t)row * 256 + ((c16 ^ (row & 7)) << 4));
      } else if (idx < 10240) {
        int i2 = idx - 8192;
        int row = i2 >> 4, c16 = i2 & 15;
        const float* s = w_fus + (size_t)row * 640 + 512 + c16 * 8;
        const float4 a = *(const float4*)(s);
        const float4 b = *(const float4*)(s + 4);
        bf16x8_store(a, b, (char*)wf2o + (size_t)row * 256 + ((c16 ^ (row & 7)) << 4));
      }
    } else if (blk < 154) {                   // dwt[p][tap][c]
      int idx = (blk - 136) * 256 + tid;
      if (idx < 4608) {
        int p = idx / 1152, rem = idx - p * 1152;
        int tap = rem >> 7, c = rem & 127;
        dwt[idx] = dw_w[(size_t)(p * 128 + c) * 9 + tap];
      }
    } else {                                  // sfus
      if (tid < 128) {
        float s = 0;
        for (int p = 0; p < 128; ++p) s += w_fus[(size_t)tid * 640 + 512 + p];
        sfus[tid] = s;
      }
    }
    return;
  }
  {
    int oc = (gblk - 8347) * 2 + (tid >> 7);
    int w = oc >> 7, c = oc & 127;
    int t = tid & 127;            // cin
    float v[9];
#pragma unroll
    for (int j = 0; j < 9; ++j) v[j] = conv1_w[(size_t)oc * 1152 + t * 9 + j];
#pragma unroll
    for (int j = 0; j < 9; ++j) {
      unsigned short bv = f2bf(v[j]);
      size_t prow = (size_t)(w * 9 + j) * 128 + c;
      *(unsigned short*)((char*)ctp + prow * 256 + ((((t >> 3) ^ (c & 7)) << 4) + (t & 7) * 2)) = bv;
      size_t qrow = (size_t)(w * 9 + j) * 128 + t;
      *(unsigned short*)((char*)ctq + qrow * 256 + ((((c >> 3) ^ (t & 7)) << 4) + (c & 7) * 2)) = bv;
    }
  }
}

// ---------------- pass A: row sums RS[bw*32+r][cin] ----------------
__global__ __launch_bounds__(128) void rs_kernel(const unsigned short* __restrict__ xln,
    float* __restrict__ RS) {
  int blk = blockIdx.x;
  int r = blk & 31, bw = blk >> 5;
  int win = bw & 3, b = bw >> 2;
  int hw = win >> 1, wn = win & 1;
  int cin = threadIdx.x;
  const unsigned short* base = xln + (((size_t)(b * 64 + hw * 32 + r)) * 64 + wn * 32) * NC + cin;
  float s = 0;
#pragma unroll
  for (int c = 0; c < 32; ++c) s += bf2f(base[(size_t)c * NC]);
  RS[(size_t)blk * 128 + cin] = s;
}

// ---------------- gemmGT: gemmG (0..35) | tfin (36..67) ----------------
__global__ __launch_bounds__(256) void gemmGT_kernel(const unsigned short* __restrict__ Wgk,
    const unsigned short* __restrict__ CTP, const float* __restrict__ w_down,
    unsigned short* __restrict__ Gbf, float* __restrict__ U,
    const unsigned short* __restrict__ xln, const float* __restrict__ RS,
    float* __restrict__ T) {
  int gblk = blockIdx.x;
  int tid = threadIdx.x;
  if (gblk >= 36) {
    if (tid >= 128) return;
    int bw = gblk - 36;
    int win = bw & 3, b = bw >> 2;
    int hw = win >> 1, wn = win & 1;
    int cin = tid;
    const unsigned short* base = xln + (((size_t)(b * 64 + hw * 32)) * 64 + wn * 32) * NC + cin;
    float A = 0;
#pragma unroll
    for (int r = 0; r < 32; ++r) A += RS[(size_t)(bw * 32 + r) * 128 + cin];
    float r0  = RS[(size_t)(bw * 32) * 128 + cin];
    float r31 = RS[(size_t)(bw * 32 + 31) * 128 + cin];
    float c0 = 0, c31 = 0;
#pragma unroll
    for (int r = 0; r < 32; ++r) {
      c0  += bf2f(base[((size_t)r * 64) * NC]);
      c31 += bf2f(base[((size_t)r * 64 + 31) * NC]);
    }
    float x00 = bf2f(base[0]);
    float x0c = bf2f(base[(size_t)31 * NC]);
    float xr0 = bf2f(base[((size_t)31 * 64) * NC]);
    float xrc = bf2f(base[((size_t)31 * 64 + 31) * NC]);
    float* t = T + ((size_t)bw * 128 + cin) * 9;
    t[0] = A - r31 - c31 + xrc;
    t[1] = A - r31;
    t[2] = A - r31 - c0 + xr0;
    t[3] = A - c31;
    t[4] = A;
    t[5] = A - c0;
    t[6] = A - r0 - c31 + x0c;
    t[7] = A - r0;
    t[8] = A - r0 - c0 + x00;
    return;
  }
  __shared__ uint4 LA[2048];
  __shared__ uint4 LB[2048];
  int bx = gblk;
  int w = bx / 9;
  int wv = tid >> 6, l = tid & 63;
  const char* ga = (const char*)Wgk + (size_t)w * 32768;
  const char* gb = (const char*)CTP + (size_t)bx * 32768;
  for (int i = wv; i < 32; i += 4) gld16(ga + (i << 10) + l * 16, (char*)LA + (i << 10));
  for (int i = wv; i < 32; i += 4) gld16(gb + (i << 10) + l * 16, (char*)LB + (i << 10));
  __syncthreads();
  const f32x4 zero = {0.f, 0.f, 0.f, 0.f};
  f32x4 acc[2][8];
#pragma unroll
  for (int mt = 0; mt < 2; ++mt)
#pragma unroll
    for (int nt = 0; nt < 8; ++nt) acc[mt][nt] = zero;
  bf16x8 af[2][4];
#pragma unroll
  for (int mt = 0; mt < 2; ++mt) {
    int r = wv * 16 + mt * 64 + (l & 15);
#pragma unroll
    for (int ks = 0; ks < 4; ++ks) {
      int c16 = ks * 4 + (l >> 4);
      af[mt][ks] = *(const bf16x8*)((const char*)LA + r * 256 + ((c16 ^ (r & 7)) << 4));
    }
  }
#pragma unroll
  for (int nt = 0; nt < 8; ++nt) {
    int n = nt * 16 + (l & 15);
    bf16x8 bq[4];
#pragma unroll
    for (int ks = 0; ks < 4; ++ks) {
      int c16 = ks * 4 + (l >> 4);
      bq[ks] = *(const bf16x8*)((const char*)LB + n * 256 + ((c16 ^ (n & 7)) << 4));
    }
#pragma unroll
    for (int ks = 0; ks < 4; ++ks)
#pragma unroll
      for (int mt = 0; mt < 2; ++mt)
        acc[mt][nt] = __builtin_amdgcn_mfma_f32_16x16x32_bf16(af[mt][ks], bq[ks], acc[mt][nt], 0, 0, 0);
  }
  char* gout = (char*)Gbf + (size_t)bx * 32768;
#pragma unroll
  for (int mt = 0; mt < 2; ++mt)
#pragma unroll
    for (int nt = 0; nt < 8; ++nt) {
      int p = nt * 16 + (l & 15);
#pragma unroll
      for (int r2 = 0; r2 < 4; ++r2) {
        int q = wv * 16 + mt * 64 + (l >> 4) * 4 + r2;
        *(unsigned short*)(gout + q * 256 + ((((p >> 3) ^ (q & 7)) << 4) + (p & 7) * 2)) =
            f2bf(acc[mt][nt][r2]);
      }
    }
  if (tid < 128) {
    int cin = tid;
    int hi = cin >> 3, lo = (cin & 7) * 2;
    float s = 0;
    for (int cout = 0; cout < 128; ++cout) {
      unsigned short bv = *(const unsigned short*)((const char*)LB + cout * 256 +
                                                   (((hi ^ (cout & 7)) << 4) + lo));
      s += w_down[w * 128 + cout] * bf2f(bv);
    }
    U[(size_t)bx * 128 + cin] = s;
  }
}

// ---------------- gemmAWse: gemmAW (0..35) | se (36) ----------------
__global__ __launch_bounds__(256) void gemmAWse_kernel(const unsigned short* __restrict__ Wf1,
    const unsigned short* __restrict__ CTQ, const unsigned short* __restrict__ Wf2,
    const unsigned short* __restrict__ Gbf, float* __restrict__ AW,
    const float* __restrict__ T, const float* __restrict__ U,
    const float* __restrict__ b_down, const float* __restrict__ w1,
    const float* __restrict__ b1, const float* __restrict__ w2,
    const float* __restrict__ b2, float* __restrict__ wgt) {
  __shared__ uint4 LA[2048];
  __shared__ uint4 LB[2048];
  int gblk = blockIdx.x;
  int tid = threadIdx.x;
  if (gblk == 36) {
    float* ydot = (float*)LA;
    int pair = tid >> 3, sub = tid & 7;
    int g = pair & 3;
    float acc = 0;
    for (int k = 0; k < 16; ++k) {
      int cin = sub * 16 + k;
      const float* tp = T + ((size_t)pair * 128 + cin) * 9;
#pragma unroll
      for (int ij = 0; ij < 9; ++ij)
        acc += U[(size_t)(g * 9 + ij) * 128 + cin] * tp[ij];
    }
#pragma unroll
    for (int off = 4; off > 0; off >>= 1) acc += __shfl_down(acc, off);
    if (sub == 0) ydot[pair] = acc;
    __syncthreads();
    if (tid < NB) {
      int b = tid;
      float y[4];
#pragma unroll
      for (int gg = 0; gg < 4; ++gg) y[gg] = ydot[b * 4 + gg] * (1.f / 1024.f) + b_down[gg];
      float y1[16];
#pragma unroll
      for (int i = 0; i < 16; ++i) {
        float a = b1[i];
#pragma unroll
        for (int gg = 0; gg < 4; ++gg) a += y[gg] * w1[i * 4 + gg];
        y1[i] = gelu_f(a);
      }
#pragma unroll
      for (int gg = 0; gg < 4; ++gg) {
        float a = b2[gg];
#pragma unroll
        for (int i = 0; i < 16; ++i) a += y1[i] * w2[gg * 16 + i];
        wgt[b * 4 + gg] = sigmoid_f(a);
      }
    }
    return;
  }
  int bx = gblk;
  int w = bx / 9;
  int wv = tid >> 6, l = tid & 63;
  const f32x4 zero = {0.f, 0.f, 0.f, 0.f};
  f32x4 acc[2][8];
#pragma unroll
  for (int mt = 0; mt < 2; ++mt)
#pragma unroll
    for (int nt = 0; nt < 8; ++nt) acc[mt][nt] = zero;
  for (int ph = 0; ph < 2; ++ph) {
    if (ph) __syncthreads();
    const char* ga = ph ? (const char*)Wf2 : (const char*)Wf1 + (size_t)w * 32768;
    const char* gb = ph ? (const char*)Gbf + (size_t)bx * 32768
                        : (const char*)CTQ + (size_t)bx * 32768;
    for (int i = wv; i < 32; i += 4) gld16(ga + (i << 10) + l * 16, (char*)LA + (i << 10));
    for (int i = wv; i < 32; i += 4) gld16(gb + (i << 10) + l * 16, (char*)LB + (i << 10));
    __syncthreads();
    bf16x8 af[2][4];
#pragma unroll
    for (int mt = 0; mt < 2; ++mt) {
      int r = wv * 16 + mt * 64 + (l & 15);
#pragma unroll
      for (int ks = 0; ks < 4; ++ks) {
        int c16 = ks * 4 + (l >> 4);
        af[mt][ks] = *(const bf16x8*)((const char*)LA + r * 256 + ((c16 ^ (r & 7)) << 4));
      }
    }
#pragma unroll
    for (int nt = 0; nt < 8; ++nt) {
      int n = nt * 16 + (l & 15);
      bf16x8 bq[4];
#pragma unroll
      for (int ks = 0; ks < 4; ++ks) {
        int c16 = ks * 4 + (l >> 4);
        bq[ks] = *(const bf16x8*)((const char*)LB + n * 256 + ((c16 ^ (n & 7)) << 4));
      }
#pragma unroll
      for (int ks = 0; ks < 4; ++ks)
#pragma unroll
        for (int mt = 0; mt < 2; ++mt)
          acc[mt][nt] = __builtin_amdgcn_mfma_f32_16x16x32_bf16(af[mt][ks], bq[ks], acc[mt][nt], 0, 0, 0);
    }
  }
  float* aout = AW + (size_t)bx * 16384;
#pragma unroll
  for (int mt = 0; mt < 2; ++mt)
#pragma unroll
    for (int nt = 0; nt < 8; ++nt) {
      int q = nt * 16 + (l & 15);
#pragma unroll
      for (int r2 = 0; r2 < 4; ++r2) {
        int o = wv * 16 + mt * 64 + (l >> 4) * 4 + r2;
        aout[(size_t)o * 128 + q] = acc[mt][nt][r2];
      }
    }
}

// ---------------- M -> bf16, LINEAR [b][ij][oc][q] ----------------
__global__ __launch_bounds__(128) void m_kernel(const float* __restrict__ AW,
    const float* __restrict__ wgt, const float* __restrict__ sfus,
    const float* __restrict__ b_gk, unsigned short* __restrict__ Mb) {
  int blk = blockIdx.x;
  int b = blk >> 7;
  int o = blk & 127;
  int q = threadIdx.x;
  float a3 = sfus[o] * b_gk[q];
  float acc[9];
#pragma unroll
  for (int ij = 0; ij < 9; ++ij) acc[ij] = a3;
#pragma unroll
  for (int w = 0; w < 4; ++w) {
    float wv = wgt[b * 4 + w];
#pragma unroll
    for (int ij = 0; ij < 9; ++ij)
      acc[ij] += wv * AW[(((size_t)(w * 9 + ij) * 128 + o) * 128) + q];
  }
#pragma unroll
  for (int ij = 0; ij < 9; ++ij)
    Mb[(((size_t)(b * 9 + ij) * NC + o) * NC) + q] = f2bf(acc[ij]);
}

// ---------------- MFMA dynamic 3x3 conv + residual(bf16) + fused LN2 ----------------
// M read DIRECTLY from global (L2-resident); no MT LDS, no in-loop barriers.
// wave = 32 spatial x 64 oc (sh = wv>>1 spatial half, oh = wv&1 oc half)
__global__ __launch_bounds__(256) void conv_kernel(const float* __restrict__ x0,
    const unsigned short* __restrict__ xln, const unsigned short* __restrict__ Mb,
    const float* __restrict__ b_fus, const float* __restrict__ ln2g,
    const float* __restrict__ ln2b, unsigned short* __restrict__ xatt,
    unsigned short* __restrict__ xln2) {
  __shared__ uint4 XT[1600];     // 25.6 KB
  int bx = blockIdx.x;
  int b = bx >> 6, tile = bx & 63;
  int by = (tile >> 3) * 8, bxc = (tile & 7) * 8;
  int tid = threadIdx.x, wv = tid >> 6, l = tid & 63;
  int sh = wv >> 1, oh = wv & 1;
  for (int i = tid; i < 1600; i += 256) {
    int cell = i >> 4, c16 = i & 15;
    int pr = cell / 10, pc = cell - pr * 10;
    int gy = by + pr - 1, gx = bxc + pc - 1;
    uint4 v = make_uint4(0, 0, 0, 0);
    if ((unsigned)gy < 64u && (unsigned)gx < 64u)
      v = *(const uint4*)(xln + (((size_t)b * NL + gy * 64 + gx) * NC + c16 * 8));
    *(uint4*)((char*)XT + cell * 256 + ((c16 ^ (cell & 7)) << 4)) = v;
  }
  const char* mg = (const char*)Mb + (size_t)b * 9 * 32768;
  __syncthreads();

  const f32x4 zero = {0.f, 0.f, 0.f, 0.f};
  f32x4 acc[2][4];
#pragma unroll
  for (int mt = 0; mt < 2; ++mt)
#pragma unroll
    for (int nt = 0; nt < 4; ++nt) acc[mt][nt] = zero;

  for (int ij = 0; ij < 9; ++ij) {
    int di = ij / 3, dj = ij - di * 3;
    const char* mbase = mg + (size_t)ij * 32768;
    bf16x8 af[2][4];
#pragma unroll
    for (int mt = 0; mt < 2; ++mt) {
      int sp = sh * 32 + mt * 16 + (l & 15);
      int cell = ((sp >> 3) + di) * 10 + (sp & 7) + dj;
#pragma unroll
      for (int ks = 0; ks < 4; ++ks) {
        int c16 = ks * 4 + (l >> 4);
        af[mt][ks] = *(const bf16x8*)((const char*)XT + cell * 256 + ((c16 ^ (cell & 7)) << 4));
      }
    }
#pragma unroll
    for (int nt = 0; nt < 4; ++nt) {
      int oc = oh * 64 + nt * 16 + (l & 15);
      bf16x8 bq[4];
#pragma unroll
      for (int ks = 0; ks < 4; ++ks) {
        int c16 = ks * 4 + (l >> 4);
        bq[ks] = *(const bf16x8*)(mbase + (size_t)oc * 256 + c16 * 16);
      }
#pragma unroll
      for (int ks = 0; ks < 4; ++ks)
#pragma unroll
        for (int mt = 0; mt < 2; ++mt)
          acc[mt][nt] = __builtin_amdgcn_mfma_f32_16x16x32_bf16(af[mt][ks], bq[ks], acc[mt][nt], 0, 0, 0);
    }
  }
  // epilogue: residual + bias (bf16 xatt); cross-wave LN2 via LDS partials (reuse XT)
  float* pS  = (float*)XT;
  float* pSS = (float*)XT + 128;
  float s[2][4], ss2[2][4];
  float vals[2][4][4];
#pragma unroll
  for (int mt = 0; mt < 2; ++mt)
#pragma unroll
    for (int r2 = 0; r2 < 4; ++r2) { s[mt][r2] = 0.f; ss2[mt][r2] = 0.f; }
#pragma unroll
  for (int mt = 0; mt < 2; ++mt)
#pragma unroll
    for (int nt = 0; nt < 4; ++nt) {
      int oc = oh * 64 + nt * 16 + (l & 15);
      float bfv = b_fus[oc];
#pragma unroll
      for (int r2 = 0; r2 < 4; ++r2) {
        int sp2 = sh * 32 + mt * 16 + (l >> 4) * 4 + r2;
        int gy = by + (sp2 >> 3), gx = bxc + (sp2 & 7);
        size_t gi = ((size_t)b * NL + gy * 64 + gx) * NC + oc;
        float v = x0[gi] + acc[mt][nt][r2] + bfv;
        xatt[gi] = f2bf(v);
        vals[mt][nt][r2] = v;
        s[mt][r2] += v;
        ss2[mt][r2] += v * v;
      }
    }
#pragma unroll
  for (int mt = 0; mt < 2; ++mt)
#pragma unroll
    for (int r2 = 0; r2 < 4; ++r2) {
#pragma unroll
      for (int off = 1; off < 16; off <<= 1) {
        s[mt][r2]   += __shfl_xor(s[mt][r2], off);
        ss2[mt][r2] += __shfl_xor(ss2[mt][r2], off);
      }
    }
  __syncthreads();   // all XT reads done before reuse as scratch
  if ((l & 15) == 0) {
    int g = l >> 4;
#pragma unroll
    for (int mt = 0; mt < 2; ++mt)
#pragma unroll
      for (int r2 = 0; r2 < 4; ++r2) {
        int row = sh * 32 + mt * 16 + g * 4 + r2;
        pS[oh * 64 + row]  = s[mt][r2];
        pSS[oh * 64 + row] = ss2[mt][r2];
      }
  }
  __syncthreads();
  float mean[2][4], rstd[2][4];
#pragma unroll
  for (int mt = 0; mt < 2; ++mt)
#pragma unroll
    for (int r2 = 0; r2 < 4; ++r2) {
      int row = sh * 32 + mt * 16 + (l >> 4) * 4 + r2;
      float S  = pS[row] + pS[64 + row];
      float SS = pSS[row] + pSS[64 + row];
      float m = S * (1.f / 128.f);
      mean[mt][r2] = m;
      rstd[mt][r2] = rsqrtf(SS * (1.f / 128.f) - m * m + 1e-5f);
    }
#pragma unroll
  for (int mt = 0; mt < 2; ++mt)
#pragma unroll
    for (int nt = 0; nt < 4; ++nt) {
      int oc = oh * 64 + nt * 16 + (l & 15);
      float gv = ln2g[oc], bv = ln2b[oc];
      int cc16 = oc >> 3, cby = (oc & 7) * 2;
#pragma unroll
      for (int r2 = 0; r2 < 4; ++r2) {
        int sp2 = sh * 32 + mt * 16 + (l >> 4) * 4 + r2;
        int gy = by + (sp2 >> 3), gx = bxc + (sp2 & 7);
        size_t rowg = (size_t)b * NL + gy * 64 + gx;
        float o = (vals[mt][nt][r2] - mean[mt][r2]) * rstd[mt][r2] * gv + bv;
        *(unsigned short*)((char*)xln2 + rowg * 256 + (((size_t)(cc16 ^ (int)(rowg & 7))) << 4) + cby) = f2bf(o);
      }
    }
}

// ---------------- MFMA lin1 + gelu ----------------
__global__ __launch_bounds__(256) void lin1_kernel(const unsigned short* __restrict__ xa,
    const unsigned short* __restrict__ wb, const float* __restrict__ bias,
    unsigned short* __restrict__ h1p0, unsigned short* __restrict__ h1p123) {
  __shared__ uint4 XA[1024];
  __shared__ uint4 XB[2048];
  size_t rb = (size_t)blockIdx.x * 64;
  int tid = threadIdx.x, wv = tid >> 6, l = tid & 63;
  const char* ga = (const char*)xa + rb * 256;
  for (int i = wv; i < 16; i += 4) gld16(ga + (i << 10) + l * 16, (char*)XA + (i << 10));
  for (int i = wv; i < 32; i += 4) gld16((const char*)wb + (i << 10) + l * 16, (char*)XB + (i << 10));
  __syncthreads();
  int r = wv * 16 + (l & 15);
  bf16x8 af[4];
#pragma unroll
  for (int ks = 0; ks < 4; ++ks) {
    int c16 = ks * 4 + (l >> 4);
    af[ks] = *(const bf16x8*)((const char*)XA + r * 256 + ((c16 ^ (r & 7)) << 4));
  }
  const f32x4 zero = {0.f, 0.f, 0.f, 0.f};
  for (int cb = 0; cb < 4; ++cb) {
    f32x4 acc[8];
#pragma unroll
    for (int nt = 0; nt < 8; ++nt) acc[nt] = zero;
#pragma unroll
    for (int nt = 0; nt < 8; ++nt) {
      int n = nt * 16 + (l & 15);
      bf16x8 bq[4];
#pragma unroll
      for (int ks = 0; ks < 4; ++ks) {
        int c16 = ks * 4 + (l >> 4);
        bq[ks] = *(const bf16x8*)((const char*)XB + n * 256 + ((c16 ^ (n & 7)) << 4));
      }
#pragma unroll
      for (int ks = 0; ks < 4; ++ks)
        acc[nt] = __builtin_amdgcn_mfma_f32_16x16x32_bf16(af[ks], bq[ks], acc[nt], 0, 0, 0);
    }
    if (cb < 3) {
      __syncthreads();
      const char* gb = (const char*)wb + (size_t)(cb + 1) * 32768;
      for (int i = wv; i < 32; i += 4) gld16(gb + (i << 10) + l * 16, (char*)XB + (i << 10));
    }
    unsigned short* hp = (cb == 0) ? h1p0 : h1p123 + (size_t)(cb - 1) * 4194304;
#pragma unroll
    for (int nt = 0; nt < 8; ++nt) {
      int n = nt * 16 + (l & 15);
      float bsv = bias[cb * 128 + n];
#pragma unroll
      for (int r2 = 0; r2 < 4; ++r2) {
        size_t row = rb + wv * 16 + (l >> 4) * 4 + r2;
        hp[row * 128 + n] = f2bf(gelu_f(acc[nt][r2] + bsv));
      }
    }
    if (cb < 3) __syncthreads();
  }
}

// ---------------- depthwise 3x3 + gelu: LDS-staged 4-row strip, 32-ch quarter-plane ----------------
__global__ __launch_bounds__(256) void dw_kernel(const unsigned short* __restrict__ h1p0,
    const unsigned short* __restrict__ h1p123, const float* __restrict__ dwt,
    const float* __restrict__ dw_b, unsigned short* __restrict__ h2p0,
    unsigned short* __restrict__ h2p123) {
  __shared__ unsigned char HT[6 * 64 * 64];   // 24KB
  __shared__ float wsm[9][32];
  int bx = blockIdx.x;
  int cq = bx >> 7;
  int rem = bx & 127;
  int bimg = rem >> 4, ys = rem & 15;
  int p = cq >> 2, q = cq & 3;
  int y0 = ys * 4;
  int tid = threadIdx.x, wv = tid >> 6, l = tid & 63;
  const unsigned short* h1p = p ? h1p123 + (size_t)(p - 1) * 4194304 : h1p0;
  unsigned short* h2p = p ? h2p123 + (size_t)(p - 1) * 4194304 : h2p0;
  size_t ibase = (size_t)bimg * 4096;
  for (int i = tid; i < 288; i += 256)
    wsm[0][i] = dwt[(size_t)p * 1152 + (i >> 5) * 128 + q * 32 + (i & 31)];
#pragma unroll
  for (int it = 0; it < 6; ++it) {
    int cb = it * 4 + wv;
    int row = cb >> 2, colblk = cb & 3;
    int yy = y0 - 1 + row;
    int ldsbase = (row * 64 + colblk * 16) * 64;
    if ((unsigned)yy < 64u) {
      const char* src = (const char*)h1p +
          (ibase + (size_t)yy * 64 + colblk * 16 + (l >> 2)) * 256 + q * 64 + (l & 3) * 16;
      gld16(src, (char*)HT + ldsbase);
    } else {
      *(uint4*)((char*)HT + ldsbase + l * 16) = make_uint4(0, 0, 0, 0);
    }
  }
  int grp = tid >> 2, c8q = tid & 3;
  int ch0 = p * 128 + q * 32 + c8q * 8;
  const float4 bs0 = *(const float4*)(dw_b + ch0);
  const float4 bs1 = *(const float4*)(dw_b + ch0 + 4);
  __syncthreads();

  int col = grp;
#pragma unroll
  for (int r = 0; r < 4; ++r) {
    float acw[8];
    acw[0] = bs0.x; acw[1] = bs0.y; acw[2] = bs0.z; acw[3] = bs0.w;
    acw[4] = bs1.x; acw[5] = bs1.y; acw[6] = bs1.z; acw[7] = bs1.w;
#pragma unroll
    for (int dy = 0; dy < 3; ++dy) {
#pragma unroll
      for (int dx = 0; dx < 3; ++dx) {
        int xc = col + dx - 1;
        if ((unsigned)xc < 64u) {
          const uint4 u = *(const uint4*)((const char*)HT +
              (((r + dy) * 64 + xc) * 64) + c8q * 16);
          const float4 wa  = *(const float4*)(&wsm[dy * 3 + dx][c8q * 8]);
          const float4 wb2 = *(const float4*)(&wsm[dy * 3 + dx][c8q * 8 + 4]);
          acw[0] += wa.x * bflo(u.x);  acw[1] += wa.y * bfhi(u.x);
          acw[2] += wa.z * bflo(u.y);  acw[3] += wa.w * bfhi(u.y);
          acw[4] += wb2.x * bflo(u.z); acw[5] += wb2.y * bfhi(u.z);
          acw[6] += wb2.z * bflo(u.w); acw[7] += wb2.w * bfhi(u.w);
        }
      }
    }
    size_t sidx = ibase + (size_t)(y0 + r) * 64 + col;
    int c16o = q * 4 + c8q;
    unsigned int o0 = (unsigned int)f2bf(gelu_f(acw[0])) | ((unsigned int)f2bf(gelu_f(acw[1])) << 16);
    unsigned int o1 = (unsigned int)f2bf(gelu_f(acw[2])) | ((unsigned int)f2bf(gelu_f(acw[3])) << 16);
    unsigned int o2 = (unsigned int)f2bf(gelu_f(acw[4])) | ((unsigned int)f2bf(gelu_f(acw[5])) << 16);
    unsigned int o3 = (unsigned int)f2bf(gelu_f(acw[6])) | ((unsigned int)f2bf(gelu_f(acw[7])) << 16);
    *(uint4*)(h2p + sidx * 128 + ((c16o ^ (int)(sidx & 7)) << 3)) = make_uint4(o0, o1, o2, o3);
  }
}

// ---------------- MFMA lin2 + residual(bf16) + bias ----------------
__global__ __launch_bounds__(256) void lin2_kernel(const unsigned short* __restrict__ h2p0,
    const unsigned short* __restrict__ h2p123, const unsigned short* __restrict__ wb,
    const float* __restrict__ bias, const unsigned short* __restrict__ xres,
    float* __restrict__ out) {
  __shared__ uint4 XA[1024];
  __shared__ uint4 XB[2048];
  size_t rb = (size_t)blockIdx.x * 64;
  int tid = threadIdx.x, wv = tid >> 6, l = tid & 63;
  const f32x4 zero = {0.f, 0.f, 0.f, 0.f};
  f32x4 acc[8];
#pragma unroll
  for (int nt = 0; nt < 8; ++nt) acc[nt] = zero;
  int r = wv * 16 + (l & 15);
  for (int kt = 0; kt < 4; ++kt) {
    if (kt) __syncthreads();
    const unsigned short* hp = (kt == 0) ? h2p0 : h2p123 + (size_t)(kt - 1) * 4194304;
    const char* ga = (const char*)hp + rb * 256;
    const char* gb = (const char*)wb + (size_t)kt * 32768;
    for (int i = wv; i < 16; i += 4) gld16(ga + (i << 10) + l * 16, (char*)XA + (i << 10));
    for (int i = wv; i < 32; i += 4) gld16(gb + (i << 10) + l * 16, (char*)XB + (i << 10));
    __syncthreads();
    bf16x8 af[4];
#pragma unroll
    for (int ks = 0; ks < 4; ++ks) {
      int c16 = ks * 4 + (l >> 4);
      af[ks] = *(const bf16x8*)((const char*)XA + r * 256 + ((c16 ^ (r & 7)) << 4));
    }
#pragma unroll
    for (int nt = 0; nt < 8; ++nt) {
      int n = nt * 16 + (l & 15);
      bf16x8 bq[4];
#pragma unroll
      for (int ks = 0; ks < 4; ++ks) {
        int c16 = ks * 4 + (l >> 4);
        bq[ks] = *(const bf16x8*)((const char*)XB + n * 256 + ((c16 ^ (n & 7)) << 4));
      }
#pragma unroll
      for (int ks = 0; ks < 4; ++ks)
        acc[nt] = __builtin_amdgcn_mfma_f32_16x16x32_bf16(af[ks], bq[ks], acc[nt], 0, 0, 0);
    }
  }
#pragma unroll
  for (int nt = 0; nt < 8; ++nt) {
    int n = nt * 16 + (l & 15);
    float bsv = bias[n];
#pragma unroll
    for (int r2 = 0; r2 < 4; ++r2) {
      size_t row = rb + wv * 16 + (l >> 4) * 4 + r2;
      size_t gi = row * NC + n;
      out[gi] = bf2f(xres[gi]) + acc[nt][r2] + bsv;
    }
  }
}

extern "C" void kernel_launch(void* const* d_in, const int* in_sizes, int n_in,
                              void* d_out, int out_size, void* d_ws, size_t ws_size,
                              hipStream_t stream) {
  (void)in_sizes; (void)n_in; (void)out_size; (void)ws_size;
  const float* x       = (const float*)d_in[0];
  const float* ln1_g   = (const float*)d_in[1];
  const float* ln1_b   = (const float*)d_in[2];
  const float* conv1_w = (const float*)d_in[3];
  const float* w_down  = (const float*)d_in[4];
  const float* b_down  = (const float*)d_in[5];
  const float* w1      = (const float*)d_in[6];
  const float* b1      = (const float*)d_in[7];
  const float* w2      = (const float*)d_in[8];
  const float* b2      = (const float*)d_in[9];
  const float* w_gk    = (const float*)d_in[10];
  const float* b_gk    = (const float*)d_in[11];
  const float* w_fus   = (const float*)d_in[12];
  const float* b_fus   = (const float*)d_in[13];
  const float* ln2_g   = (const float*)d_in[14];
  const float* ln2_b   = (const float*)d_in[15];
  const float* lin1_w  = (const float*)d_in[16];
  const float* lin1_b  = (const float*)d_in[17];
  const float* dw_w    = (const float*)d_in[18];
  const float* dw_b    = (const float*)d_in[19];
  const float* lin2_w  = (const float*)d_in[20];
  const float* lin2_b  = (const float*)d_in[21];
  float* out = (float*)d_out;
  char* ws = (char*)d_ws;

  unsigned short* xatt_bf = (unsigned short*)(ws);           // 8,388,608 (bf16)
  float*          Tb      = (float*)(ws + 16777216);         // 147,456
  float*          wgtb    = (float*)(ws + 16924672);         // 512
  float*          sfus    = (float*)(ws + 16925184);         // 512
  float*          dwt     = (float*)(ws + 16925696);         // 18,432
  unsigned short* Wgk_bf  = (unsigned short*)(ws + 16944128);// 131,072
  unsigned short* Wf1_bf  = (unsigned short*)(ws + 17075200);// 131,072
  unsigned short* Wf2_bf  = (unsigned short*)(ws + 17206272);// 32,768
  unsigned short* w1_bf   = (unsigned short*)(ws + 17239040);// 131,072
  unsigned short* w2_bf   = (unsigned short*)(ws + 17370112);// 131,072
  unsigned short* M_bf    = (unsigned short*)(ws + 17501184);// 2,359,296
  unsigned short* xln_bf  = (unsigned short*)(ws + 19860480);// 8,388,608 (reused as h1 plane0)
  unsigned short* xln2_bf = (unsigned short*)(ws + 28249088);// 8,388,608 (early: scratch; conv LN2 out; later h2 plane0)
  unsigned short* h1p123  = (unsigned short*)(ws + 36637696);// 25,165,824
  unsigned short* h2p123  = (unsigned short*)(ws + 61803520);// 25,165,824
  char* sc = ws + 28249088;
  float*          RSb     = (float*)(sc);                    // 524,288
  float*          Ub      = (float*)(sc + 524288);           // 18,432
  unsigned short* CTP_bf  = (unsigned short*)(sc + 542720);  // 1,179,648
  unsigned short* CTQ_bf  = (unsigned short*)(sc + 1722368); // 1,179,648
  unsigned short* G_bf    = (unsigned short*)(sc + 2902016); // 1,179,648
  float*          AWb     = (float*)(sc + 4081664);          // 2,359,296

  head_kernel<<<8603, 256, 0, stream>>>(x, ln1_g, ln1_b, xln_bf,
                                        lin1_w, lin2_w, w_gk, w_fus, dw_w, conv1_w,
                                        w1_bf, w2_bf, Wgk_bf, Wf1_bf, Wf2_bf, dwt, sfus,
                                        CTP_bf, CTQ_bf);
  rs_kernel<<<1024, 128, 0, stream>>>(xln_bf, RSb);
  gemmGT_kernel<<<68, 256, 0, stream>>>(Wgk_bf, CTP_bf, w_down, G_bf, Ub,
                                        xln_bf, RSb, Tb);
  gemmAWse_kernel<<<37, 256, 0, stream>>>(Wf1_bf, CTQ_bf, Wf2_bf, G_bf, AWb,
                                          Tb, Ub, b_down, w1, b1, w2, b2, wgtb);
  m_kernel<<<1024, 128, 0, stream>>>(AWb, wgtb, sfus, b_gk, M_bf);
  conv_kernel<<<512, 256, 0, stream>>>(x, xln_bf, M_bf, b_fus, ln2_g, ln2_b, xatt_bf, xln2_bf);
  lin1_kernel<<<512, 256, 0, stream>>>(xln2_bf, w1_bf, lin1_b, xln_bf /*h1 p0*/, h1p123);
  dw_kernel<<<2048, 256, 0, stream>>>(xln_bf /*h1 p0*/, h1p123, dwt, dw_b,
                                      xln2_bf /*h2 p0*/, h2p123);
  lin2_kernel<<<512, 256, 0, stream>>>(xln2_bf /*h2 p0*/, h2p123, w2_bf, lin2_b, xatt_bf, out);
}

// Round 16
// 136.539 us; speedup vs baseline: 1.1529x; 1.1529x over previous
//
#include <hip/hip_runtime.h>
#include <math.h>

#define NB   8
#define HH   64
#define NC   128
#define NHID 512
#define NL   4096

typedef __attribute__((ext_vector_type(4))) float f32x4;
typedef __attribute__((ext_vector_type(8))) __bf16 bf16x8;

__device__ __forceinline__ float gelu_f(float v) {
  return 0.5f * v * (1.f + erff(v * 0.70710678118654752f));
}
__device__ __forceinline__ float sigmoid_f(float v) {
  return 1.f / (1.f + expf(-v));
}
__device__ __forceinline__ unsigned short f2bf(float f) {
  unsigned int u = __builtin_bit_cast(unsigned int, f);
  unsigned int r = (u + 0x7FFFu + ((u >> 16) & 1u)) >> 16;
  return (unsigned short)r;
}
__device__ __forceinline__ float bf2f(unsigned short h) {
  return __builtin_bit_cast(float, ((unsigned int)h) << 16);
}
__device__ __forceinline__ float bflo(unsigned int w) {
  return __builtin_bit_cast(float, w << 16);
}
__device__ __forceinline__ float bfhi(unsigned int w) {
  return __builtin_bit_cast(float, w & 0xFFFF0000u);
}
__device__ __forceinline__ void gld16(const void* g, void* l) {
  __builtin_amdgcn_global_load_lds(
      (const __attribute__((address_space(1))) unsigned int*)g,
      (__attribute__((address_space(3))) unsigned int*)l, 16, 0, 0);
}

__device__ __forceinline__ void bf16x8_store(const float4& a, const float4& b, void* dst) {
  unsigned int p0 = (unsigned int)f2bf(a.x) | ((unsigned int)f2bf(a.y) << 16);
  unsigned int p1 = (unsigned int)f2bf(a.z) | ((unsigned int)f2bf(a.w) << 16);
  unsigned int p2 = (unsigned int)f2bf(b.x) | ((unsigned int)f2bf(b.y) << 16);
  unsigned int p3 = (unsigned int)f2bf(b.z) | ((unsigned int)f2bf(b.w) << 16);
  *(uint4*)dst = make_uint4(p0, p1, p2, p3);
}

// ---------------- head: ln (0..8191) | prep_misc (8192..8346) | prep_ct (8347..8602) ----------------
__global__ __launch_bounds__(256) void head_kernel(const float* __restrict__ x,
    const float* __restrict__ ln1_g, const float* __restrict__ ln1_b,
    unsigned short* __restrict__ xln,
    const float* __restrict__ lin1_w, const float* __restrict__ lin2_w,
    const float* __restrict__ w_gk, const float* __restrict__ w_fus,
    const float* __restrict__ dw_w, const float* __restrict__ conv1_w,
    unsigned short* __restrict__ w1o, unsigned short* __restrict__ w2o,
    unsigned short* __restrict__ wgko, unsigned short* __restrict__ wf1o,
    unsigned short* __restrict__ wf2o, float* __restrict__ dwt,
    float* __restrict__ sfus,
    unsigned short* __restrict__ ctp, unsigned short* __restrict__ ctq) {
  int gblk = blockIdx.x, tid = threadIdx.x;
  if (gblk < 8192) {
    int wv = tid >> 6, l = tid & 63;
    int row = gblk * 4 + wv;
    const float2 v = *(const float2*)(x + (size_t)row * NC + l * 2);
    float s = v.x + v.y, ss = v.x * v.x + v.y * v.y;
#pragma unroll
    for (int off = 32; off > 0; off >>= 1) {
      s  += __shfl_down(s, off);
      ss += __shfl_down(ss, off);
    }
    s = __shfl(s, 0); ss = __shfl(ss, 0);
    float mean = s * (1.f / NC);
    float rstd = rsqrtf(ss * (1.f / NC) - mean * mean + 1e-5f);
    const float2 gg = *(const float2*)(ln1_g + l * 2);
    const float2 bv = *(const float2*)(ln1_b + l * 2);
    float o0 = (v.x - mean) * rstd * gg.x + bv.x;
    float o1 = (v.y - mean) * rstd * gg.y + bv.y;
    unsigned int pk = (unsigned int)f2bf(o0) | ((unsigned int)f2bf(o1) << 16);
    *(unsigned int*)((char*)xln + (size_t)row * 256 + ((l >> 2) << 4) + (l & 3) * 4) = pk;
    return;
  }
  if (gblk < 8347) {
    int blk = gblk - 8192;
    if (blk < 32) {                           // w1
      int idx = blk * 256 + tid;
      int n = idx >> 4, c16 = idx & 15;
      const float4 a = *(const float4*)(lin1_w + (size_t)n * 128 + c16 * 8);
      const float4 b = *(const float4*)(lin1_w + (size_t)n * 128 + c16 * 8 + 4);
      bf16x8_store(a, b, (char*)w1o + (size_t)n * 256 + ((c16 ^ (n & 7)) << 4));
    } else if (blk < 64) {                    // w2 blocked by kt
      int idx = (blk - 32) * 256 + tid;
      int kt = idx >> 11, c = (idx >> 4) & 127, c16 = idx & 15;
      const float* s = lin2_w + (size_t)c * NHID + kt * 128 + c16 * 8;
      const float4 a = *(const float4*)(s);
      const float4 b = *(const float4*)(s + 4);
      bf16x8_store(a, b, (char*)w2o + (size_t)(kt * 128 + c) * 256 + ((c16 ^ (c & 7)) << 4));
    } else if (blk < 96) {                    // wgk
      int idx = (blk - 64) * 256 + tid;
      int row = idx >> 4, c16 = idx & 15;
      int w = row >> 7, q = row & 127;
      const float* s = w_gk + (size_t)q * 512 + w * 128 + c16 * 8;
      const float4 a = *(const float4*)(s);
      const float4 b = *(const float4*)(s + 4);
      bf16x8_store(a, b, (char*)wgko + (size_t)row * 256 + ((c16 ^ (row & 7)) << 4));
    } else if (blk < 136) {                   // wf1 + wf2
      int idx = (blk - 96) * 256 + tid;
      if (idx < 8192) {
        int row = idx >> 4, c16 = idx & 15;
        int w = row >> 7, o = row & 127;
        const float* s = w_fus + (size_t)o * 640 + w * 128 + c16 * 8;
        const float4 a = *(const float4*)(s);
        const float4 b = *(const float4*)(s + 4);
        bf16x8_store(a, b, (char*)wf1o + (size_t)row * 256 + ((c16 ^ (row & 7)) << 4));
      } else if (idx < 10240) {
        int i2 = idx - 8192;
        int row = i2 >> 4, c16 = i2 & 15;
        const float* s = w_fus + (size_t)row * 640 + 512 + c16 * 8;
        const float4 a = *(const float4*)(s);
        const float4 b = *(const float4*)(s + 4);
        bf16x8_store(a, b, (char*)wf2o + (size_t)row * 256 + ((c16 ^ (row & 7)) << 4));
      }
    } else if (blk < 154) {                   // dwt[p][tap][c]
      int idx = (blk - 136) * 256 + tid;
      if (idx < 4608) {
        int p = idx / 1152, rem = idx - p * 1152;
        int tap = rem >> 7, c = rem & 127;
        dwt[idx] = dw_w[(size_t)(p * 128 + c) * 9 + tap];
      }
    } else {                                  // sfus
      if (tid < 128) {
        float s = 0;
        for (int p = 0; p < 128; ++p) s += w_fus[(size_t)tid * 640 + 512 + p];
        sfus[tid] = s;
      }
    }
    return;
  }
  {
    int oc = (gblk - 8347) * 2 + (tid >> 7);
    int w = oc >> 7, c = oc & 127;
    int t = tid & 127;            // cin
    float v[9];
#pragma unroll
    for (int j = 0; j < 9; ++j) v[j] = conv1_w[(size_t)oc * 1152 + t * 9 + j];
#pragma unroll
    for (int j = 0; j < 9; ++j) {
      unsigned short bv = f2bf(v[j]);
      size_t prow = (size_t)(w * 9 + j) * 128 + c;
      *(unsigned short*)((char*)ctp + prow * 256 + ((((t >> 3) ^ (c & 7)) << 4) + (t & 7) * 2)) = bv;
      size_t qrow = (size_t)(w * 9 + j) * 128 + t;
      *(unsigned short*)((char*)ctq + qrow * 256 + ((((c >> 3) ^ (t & 7)) << 4) + (c & 7) * 2)) = bv;
    }
  }
}

// ---------------- pass A: row sums RS[bw*32+r][cin] ----------------
__global__ __launch_bounds__(128) void rs_kernel(const unsigned short* __restrict__ xln,
    float* __restrict__ RS) {
  int blk = blockIdx.x;
  int r = blk & 31, bw = blk >> 5;
  int win = bw & 3, b = bw >> 2;
  int hw = win >> 1, wn = win & 1;
  int cin = threadIdx.x;
  const unsigned short* base = xln + (((size_t)(b * 64 + hw * 32 + r)) * 64 + wn * 32) * NC + cin;
  float s = 0;
#pragma unroll
  for (int c = 0; c < 32; ++c) s += bf2f(base[(size_t)c * NC]);
  RS[(size_t)blk * 128 + cin] = s;
}

// ---------------- gemmGT: gemmG (0..35) | tfin (36..67) ----------------
__global__ __launch_bounds__(256) void gemmGT_kernel(const unsigned short* __restrict__ Wgk,
    const unsigned short* __restrict__ CTP, const float* __restrict__ w_down,
    unsigned short* __restrict__ Gbf, float* __restrict__ U,
    const unsigned short* __restrict__ xln, const float* __restrict__ RS,
    float* __restrict__ T) {
  int gblk = blockIdx.x;
  int tid = threadIdx.x;
  if (gblk >= 36) {
    if (tid >= 128) return;
    int bw = gblk - 36;
    int win = bw & 3, b = bw >> 2;
    int hw = win >> 1, wn = win & 1;
    int cin = tid;
    const unsigned short* base = xln + (((size_t)(b * 64 + hw * 32)) * 64 + wn * 32) * NC + cin;
    float A = 0;
#pragma unroll
    for (int r = 0; r < 32; ++r) A += RS[(size_t)(bw * 32 + r) * 128 + cin];
    float r0  = RS[(size_t)(bw * 32) * 128 + cin];
    float r31 = RS[(size_t)(bw * 32 + 31) * 128 + cin];
    float c0 = 0, c31 = 0;
#pragma unroll
    for (int r = 0; r < 32; ++r) {
      c0  += bf2f(base[((size_t)r * 64) * NC]);
      c31 += bf2f(base[((size_t)r * 64 + 31) * NC]);
    }
    float x00 = bf2f(base[0]);
    float x0c = bf2f(base[(size_t)31 * NC]);
    float xr0 = bf2f(base[((size_t)31 * 64) * NC]);
    float xrc = bf2f(base[((size_t)31 * 64 + 31) * NC]);
    float* t = T + ((size_t)bw * 128 + cin) * 9;
    t[0] = A - r31 - c31 + xrc;
    t[1] = A - r31;
    t[2] = A - r31 - c0 + xr0;
    t[3] = A - c31;
    t[4] = A;
    t[5] = A - c0;
    t[6] = A - r0 - c31 + x0c;
    t[7] = A - r0;
    t[8] = A - r0 - c0 + x00;
    return;
  }
  __shared__ uint4 LA[2048];
  __shared__ uint4 LB[2048];
  int bx = gblk;
  int w = bx / 9;
  int wv = tid >> 6, l = tid & 63;
  const char* ga = (const char*)Wgk + (size_t)w * 32768;
  const char* gb = (const char*)CTP + (size_t)bx * 32768;
  for (int i = wv; i < 32; i += 4) gld16(ga + (i << 10) + l * 16, (char*)LA + (i << 10));
  for (int i = wv; i < 32; i += 4) gld16(gb + (i << 10) + l * 16, (char*)LB + (i << 10));
  __syncthreads();
  const f32x4 zero = {0.f, 0.f, 0.f, 0.f};
  f32x4 acc[2][8];
#pragma unroll
  for (int mt = 0; mt < 2; ++mt)
#pragma unroll
    for (int nt = 0; nt < 8; ++nt) acc[mt][nt] = zero;
  bf16x8 af[2][4];
#pragma unroll
  for (int mt = 0; mt < 2; ++mt) {
    int r = wv * 16 + mt * 64 + (l & 15);
#pragma unroll
    for (int ks = 0; ks < 4; ++ks) {
      int c16 = ks * 4 + (l >> 4);
      af[mt][ks] = *(const bf16x8*)((const char*)LA + r * 256 + ((c16 ^ (r & 7)) << 4));
    }
  }
#pragma unroll
  for (int nt = 0; nt < 8; ++nt) {
    int n = nt * 16 + (l & 15);
    bf16x8 bq[4];
#pragma unroll
    for (int ks = 0; ks < 4; ++ks) {
      int c16 = ks * 4 + (l >> 4);
      bq[ks] = *(const bf16x8*)((const char*)LB + n * 256 + ((c16 ^ (n & 7)) << 4));
    }
#pragma unroll
    for (int ks = 0; ks < 4; ++ks)
#pragma unroll
      for (int mt = 0; mt < 2; ++mt)
        acc[mt][nt] = __builtin_amdgcn_mfma_f32_16x16x32_bf16(af[mt][ks], bq[ks], acc[mt][nt], 0, 0, 0);
  }
  char* gout = (char*)Gbf + (size_t)bx * 32768;
#pragma unroll
  for (int mt = 0; mt < 2; ++mt)
#pragma unroll
    for (int nt = 0; nt < 8; ++nt) {
      int p = nt * 16 + (l & 15);
#pragma unroll
      for (int r2 = 0; r2 < 4; ++r2) {
        int q = wv * 16 + mt * 64 + (l >> 4) * 4 + r2;
        *(unsigned short*)(gout + q * 256 + ((((p >> 3) ^ (q & 7)) << 4) + (p & 7) * 2)) =
            f2bf(acc[mt][nt][r2]);
      }
    }
  if (tid < 128) {
    int cin = tid;
    int hi = cin >> 3, lo = (cin & 7) * 2;
    float s = 0;
    for (int cout = 0; cout < 128; ++cout) {
      unsigned short bv = *(const unsigned short*)((const char*)LB + cout * 256 +
                                                   (((hi ^ (cout & 7)) << 4) + lo));
      s += w_down[w * 128 + cout] * bf2f(bv);
    }
    U[(size_t)bx * 128 + cin] = s;
  }
}

// ---------------- gemmAWse: gemmAW (0..35) | se (36) ----------------
__global__ __launch_bounds__(256) void gemmAWse_kernel(const unsigned short* __restrict__ Wf1,
    const unsigned short* __restrict__ CTQ, const unsigned short* __restrict__ Wf2,
    const unsigned short* __restrict__ Gbf, float* __restrict__ AW,
    const float* __restrict__ T, const float* __restrict__ U,
    const float* __restrict__ b_down, const float* __restrict__ w1,
    const float* __restrict__ b1, const float* __restrict__ w2,
    const float* __restrict__ b2, float* __restrict__ wgt) {
  __shared__ uint4 LA[2048];
  __shared__ uint4 LB[2048];
  int gblk = blockIdx.x;
  int tid = threadIdx.x;
  if (gblk == 36) {
    float* ydot = (float*)LA;
    int pair = tid >> 3, sub = tid & 7;
    int g = pair & 3;
    float acc = 0;
    for (int k = 0; k < 16; ++k) {
      int cin = sub * 16 + k;
      const float* tp = T + ((size_t)pair * 128 + cin) * 9;
#pragma unroll
      for (int ij = 0; ij < 9; ++ij)
        acc += U[(size_t)(g * 9 + ij) * 128 + cin] * tp[ij];
    }
#pragma unroll
    for (int off = 4; off > 0; off >>= 1) acc += __shfl_down(acc, off);
    if (sub == 0) ydot[pair] = acc;
    __syncthreads();
    if (tid < NB) {
      int b = tid;
      float y[4];
#pragma unroll
      for (int gg = 0; gg < 4; ++gg) y[gg] = ydot[b * 4 + gg] * (1.f / 1024.f) + b_down[gg];
      float y1[16];
#pragma unroll
      for (int i = 0; i < 16; ++i) {
        float a = b1[i];
#pragma unroll
        for (int gg = 0; gg < 4; ++gg) a += y[gg] * w1[i * 4 + gg];
        y1[i] = gelu_f(a);
      }
#pragma unroll
      for (int gg = 0; gg < 4; ++gg) {
        float a = b2[gg];
#pragma unroll
        for (int i = 0; i < 16; ++i) a += y1[i] * w2[gg * 16 + i];
        wgt[b * 4 + gg] = sigmoid_f(a);
      }
    }
    return;
  }
  int bx = gblk;
  int w = bx / 9;
  int wv = tid >> 6, l = tid & 63;
  const f32x4 zero = {0.f, 0.f, 0.f, 0.f};
  f32x4 acc[2][8];
#pragma unroll
  for (int mt = 0; mt < 2; ++mt)
#pragma unroll
    for (int nt = 0; nt < 8; ++nt) acc[mt][nt] = zero;
  for (int ph = 0; ph < 2; ++ph) {
    if (ph) __syncthreads();
    const char* ga = ph ? (const char*)Wf2 : (const char*)Wf1 + (size_t)w * 32768;
    const char* gb = ph ? (const char*)Gbf + (size_t)bx * 32768
                        : (const char*)CTQ + (size_t)bx * 32768;
    for (int i = wv; i < 32; i += 4) gld16(ga + (i << 10) + l * 16, (char*)LA + (i << 10));
    for (int i = wv; i < 32; i += 4) gld16(gb + (i << 10) + l * 16, (char*)LB + (i << 10));
    __syncthreads();
    bf16x8 af[2][4];
#pragma unroll
    for (int mt = 0; mt < 2; ++mt) {
      int r = wv * 16 + mt * 64 + (l & 15);
#pragma unroll
      for (int ks = 0; ks < 4; ++ks) {
        int c16 = ks * 4 + (l >> 4);
        af[mt][ks] = *(const bf16x8*)((const char*)LA + r * 256 + ((c16 ^ (r & 7)) << 4));
      }
    }
#pragma unroll
    for (int nt = 0; nt < 8; ++nt) {
      int n = nt * 16 + (l & 15);
      bf16x8 bq[4];
#pragma unroll
      for (int ks = 0; ks < 4; ++ks) {
        int c16 = ks * 4 + (l >> 4);
        bq[ks] = *(const bf16x8*)((const char*)LB + n * 256 + ((c16 ^ (n & 7)) << 4));
      }
#pragma unroll
      for (int ks = 0; ks < 4; ++ks)
#pragma unroll
        for (int mt = 0; mt < 2; ++mt)
          acc[mt][nt] = __builtin_amdgcn_mfma_f32_16x16x32_bf16(af[mt][ks], bq[ks], acc[mt][nt], 0, 0, 0);
    }
  }
  float* aout = AW + (size_t)bx * 16384;
#pragma unroll
  for (int mt = 0; mt < 2; ++mt)
#pragma unroll
    for (int nt = 0; nt < 8; ++nt) {
      int q = nt * 16 + (l & 15);
#pragma unroll
      for (int r2 = 0; r2 < 4; ++r2) {
        int o = wv * 16 + mt * 64 + (l >> 4) * 4 + r2;
        aout[(size_t)o * 128 + q] = acc[mt][nt][r2];
      }
    }
}

// ---------------- M -> bf16, [b][ij][oc][q] with q-chunk XOR-swizzle (key oc&7) ----------------
__global__ __launch_bounds__(128) void m_kernel(const float* __restrict__ AW,
    const float* __restrict__ wgt, const float* __restrict__ sfus,
    const float* __restrict__ b_gk, unsigned short* __restrict__ Mb) {
  int blk = blockIdx.x;
  int b = blk >> 7;
  int o = blk & 127;
  int q = threadIdx.x;
  float a3 = sfus[o] * b_gk[q];
  float acc[9];
#pragma unroll
  for (int ij = 0; ij < 9; ++ij) acc[ij] = a3;
#pragma unroll
  for (int w = 0; w < 4; ++w) {
    float wv = wgt[b * 4 + w];
#pragma unroll
    for (int ij = 0; ij < 9; ++ij)
      acc[ij] += wv * AW[(((size_t)(w * 9 + ij) * 128 + o) * 128) + q];
  }
  int qswz = (q & 7) | (((q >> 3) ^ (o & 7)) << 3);
#pragma unroll
  for (int ij = 0; ij < 9; ++ij)
    Mb[(((size_t)(b * 9 + ij) * NC + o) * NC) + qswz] = f2bf(acc[ij]);
}

// ---------------- MFMA dynamic 3x3 conv + residual(bf16) + fused LN2 (R14 schedule) ----------------
// wave = 32 spatial x 64 oc (sh = wv>>1 spatial half, oh = wv&1 oc half)
__global__ __launch_bounds__(256) void conv_kernel(const float* __restrict__ x0,
    const unsigned short* __restrict__ xln, const unsigned short* __restrict__ Mb,
    const float* __restrict__ b_fus, const float* __restrict__ ln2g,
    const float* __restrict__ ln2b, unsigned short* __restrict__ xatt,
    unsigned short* __restrict__ xln2) {
  __shared__ uint4 XT[1600];
  __shared__ uint4 MT[2048];
  int bx = blockIdx.x;
  int b = bx >> 6, tile = bx & 63;
  int by = (tile >> 3) * 8, bxc = (tile & 7) * 8;
  int tid = threadIdx.x, wv = tid >> 6, l = tid & 63;
  int sh = wv >> 1, oh = wv & 1;
  for (int i = tid; i < 1600; i += 256) {
    int cell = i >> 4, c16 = i & 15;
    int pr = cell / 10, pc = cell - pr * 10;
    int gy = by + pr - 1, gx = bxc + pc - 1;
    uint4 v = make_uint4(0, 0, 0, 0);
    if ((unsigned)gy < 64u && (unsigned)gx < 64u)
      v = *(const uint4*)(xln + (((size_t)b * NL + gy * 64 + gx) * NC + c16 * 8));
    *(uint4*)((char*)XT + cell * 256 + ((c16 ^ (cell & 7)) << 4)) = v;
  }
  const char* mg = (const char*)Mb + (size_t)b * 9 * 32768;
  for (int i = wv; i < 32; i += 4) gld16(mg + (i << 10) + l * 16, (char*)MT + (i << 10));
  __syncthreads();

  const f32x4 zero = {0.f, 0.f, 0.f, 0.f};
  f32x4 acc[2][4];
#pragma unroll
  for (int mt = 0; mt < 2; ++mt)
#pragma unroll
    for (int nt = 0; nt < 4; ++nt) acc[mt][nt] = zero;

  for (int ij = 0; ij < 9; ++ij) {
    int di = ij / 3, dj = ij - di * 3;
    bf16x8 af[2][4];
#pragma unroll
    for (int mt = 0; mt < 2; ++mt) {
      int sp = sh * 32 + mt * 16 + (l & 15);
      int cell = ((sp >> 3) + di) * 10 + (sp & 7) + dj;
#pragma unroll
      for (int ks = 0; ks < 4; ++ks) {
        int c16 = ks * 4 + (l >> 4);
        af[mt][ks] = *(const bf16x8*)((const char*)XT + cell * 256 + ((c16 ^ (cell & 7)) << 4));
      }
    }
#pragma unroll
    for (int nt = 0; nt < 4; ++nt) {
      int oc = oh * 64 + nt * 16 + (l & 15);
      bf16x8 bq[4];
#pragma unroll
      for (int ks = 0; ks < 4; ++ks) {
        int c16 = ks * 4 + (l >> 4);
        bq[ks] = *(const bf16x8*)((const char*)MT + oc * 256 + ((c16 ^ (oc & 7)) << 4));
      }
#pragma unroll
      for (int ks = 0; ks < 4; ++ks)
#pragma unroll
        for (int mt = 0; mt < 2; ++mt)
          acc[mt][nt] = __builtin_amdgcn_mfma_f32_16x16x32_bf16(af[mt][ks], bq[ks], acc[mt][nt], 0, 0, 0);
    }
    __syncthreads();
    if (ij < 8) {
      const char* mg2 = mg + (size_t)(ij + 1) * 32768;
      for (int i = wv; i < 32; i += 4) gld16(mg2 + (i << 10) + l * 16, (char*)MT + (i << 10));
    }
    __syncthreads();
  }
  // epilogue: residual + bias (bf16 xatt); cross-wave LN2 via LDS partials (reuse XT)
  float* pS  = (float*)XT;
  float* pSS = (float*)XT + 128;
  float s[2][4], ss2[2][4];
  float vals[2][4][4];
#pragma unroll
  for (int mt = 0; mt < 2; ++mt)
#pragma unroll
    for (int r2 = 0; r2 < 4; ++r2) { s[mt][r2] = 0.f; ss2[mt][r2] = 0.f; }
#pragma unroll
  for (int mt = 0; mt < 2; ++mt)
#pragma unroll
    for (int nt = 0; nt < 4; ++nt) {
      int oc = oh * 64 + nt * 16 + (l & 15);
      float bfv = b_fus[oc];
#pragma unroll
      for (int r2 = 0; r2 < 4; ++r2) {
        int sp2 = sh * 32 + mt * 16 + (l >> 4) * 4 + r2;
        int gy = by + (sp2 >> 3), gx = bxc + (sp2 & 7);
        size_t gi = ((size_t)b * NL + gy * 64 + gx) * NC + oc;
        float v = x0[gi] + acc[mt][nt][r2] + bfv;
        xatt[gi] = f2bf(v);
        vals[mt][nt][r2] = v;
        s[mt][r2] += v;
        ss2[mt][r2] += v * v;
      }
    }
#pragma unroll
  for (int mt = 0; mt < 2; ++mt)
#pragma unroll
    for (int r2 = 0; r2 < 4; ++r2) {
#pragma unroll
      for (int off = 1; off < 16; off <<= 1) {
        s[mt][r2]   += __shfl_xor(s[mt][r2], off);
        ss2[mt][r2] += __shfl_xor(ss2[mt][r2], off);
      }
    }
  if ((l & 15) == 0) {
    int g = l >> 4;
#pragma unroll
    for (int mt = 0; mt < 2; ++mt)
#pragma unroll
      for (int r2 = 0; r2 < 4; ++r2) {
        int row = sh * 32 + mt * 16 + g * 4 + r2;
        pS[oh * 64 + row]  = s[mt][r2];
        pSS[oh * 64 + row] = ss2[mt][r2];
      }
  }
  __syncthreads();
  float mean[2][4], rstd[2][4];
#pragma unroll
  for (int mt = 0; mt < 2; ++mt)
#pragma unroll
    for (int r2 = 0; r2 < 4; ++r2) {
      int row = sh * 32 + mt * 16 + (l >> 4) * 4 + r2;
      float S  = pS[row] + pS[64 + row];
      float SS = pSS[row] + pSS[64 + row];
      float m = S * (1.f / 128.f);
      mean[mt][r2] = m;
      rstd[mt][r2] = rsqrtf(SS * (1.f / 128.f) - m * m + 1e-5f);
    }
#pragma unroll
  for (int mt = 0; mt < 2; ++mt)
#pragma unroll
    for (int nt = 0; nt < 4; ++nt) {
      int oc = oh * 64 + nt * 16 + (l & 15);
      float gv = ln2g[oc], bv = ln2b[oc];
      int cc16 = oc >> 3, cby = (oc & 7) * 2;
#pragma unroll
      for (int r2 = 0; r2 < 4; ++r2) {
        int sp2 = sh * 32 + mt * 16 + (l >> 4) * 4 + r2;
        int gy = by + (sp2 >> 3), gx = bxc + (sp2 & 7);
        size_t rowg = (size_t)b * NL + gy * 64 + gx;
        float o = (vals[mt][nt][r2] - mean[mt][r2]) * rstd[mt][r2] * gv + bv;
        *(unsigned short*)((char*)xln2 + rowg * 256 + (((size_t)(cc16 ^ (int)(rowg & 7))) << 4) + cby) = f2bf(o);
      }
    }
}

// ---------------- MFMA lin1 + gelu ----------------
__global__ __launch_bounds__(256) void lin1_kernel(const unsigned short* __restrict__ xa,
    const unsigned short* __restrict__ wb, const float* __restrict__ bias,
    unsigned short* __restrict__ h1p0, unsigned short* __restrict__ h1p123) {
  __shared__ uint4 XA[1024];
  __shared__ uint4 XB[2048];
  size_t rb = (size_t)blockIdx.x * 64;
  int tid = threadIdx.x, wv = tid >> 6, l = tid & 63;
  const char* ga = (const char*)xa + rb * 256;
  for (int i = wv; i < 16; i += 4) gld16(ga + (i << 10) + l * 16, (char*)XA + (i << 10));
  for (int i = wv; i < 32; i += 4) gld16((const char*)wb + (i << 10) + l * 16, (char*)XB + (i << 10));
  __syncthreads();
  int r = wv * 16 + (l & 15);
  bf16x8 af[4];
#pragma unroll
  for (int ks = 0; ks < 4; ++ks) {
    int c16 = ks * 4 + (l >> 4);
    af[ks] = *(const bf16x8*)((const char*)XA + r * 256 + ((c16 ^ (r & 7)) << 4));
  }
  const f32x4 zero = {0.f, 0.f, 0.f, 0.f};
  for (int cb = 0; cb < 4; ++cb) {
    f32x4 acc[8];
#pragma unroll
    for (int nt = 0; nt < 8; ++nt) acc[nt] = zero;
#pragma unroll
    for (int nt = 0; nt < 8; ++nt) {
      int n = nt * 16 + (l & 15);
      bf16x8 bq[4];
#pragma unroll
      for (int ks = 0; ks < 4; ++ks) {
        int c16 = ks * 4 + (l >> 4);
        bq[ks] = *(const bf16x8*)((const char*)XB + n * 256 + ((c16 ^ (n & 7)) << 4));
      }
#pragma unroll
      for (int ks = 0; ks < 4; ++ks)
        acc[nt] = __builtin_amdgcn_mfma_f32_16x16x32_bf16(af[ks], bq[ks], acc[nt], 0, 0, 0);
    }
    if (cb < 3) {
      __syncthreads();
      const char* gb = (const char*)wb + (size_t)(cb + 1) * 32768;
      for (int i = wv; i < 32; i += 4) gld16(gb + (i << 10) + l * 16, (char*)XB + (i << 10));
    }
    unsigned short* hp = (cb == 0) ? h1p0 : h1p123 + (size_t)(cb - 1) * 4194304;
#pragma unroll
    for (int nt = 0; nt < 8; ++nt) {
      int n = nt * 16 + (l & 15);
      float bsv = bias[cb * 128 + n];
#pragma unroll
      for (int r2 = 0; r2 < 4; ++r2) {
        size_t row = rb + wv * 16 + (l >> 4) * 4 + r2;
        hp[row * 128 + n] = f2bf(gelu_f(acc[nt][r2] + bsv));
      }
    }
    if (cb < 3) __syncthreads();
  }
}

// ---------------- depthwise 3x3 + gelu: LDS-staged 4-row strip, 32-ch quarter-plane ----------------
__global__ __launch_bounds__(256) void dw_kernel(const unsigned short* __restrict__ h1p0,
    const unsigned short* __restrict__ h1p123, const float* __restrict__ dwt,
    const float* __restrict__ dw_b, unsigned short* __restrict__ h2p0,
    unsigned short* __restrict__ h2p123) {
  __shared__ unsigned char HT[6 * 64 * 64];   // 24KB
  __shared__ float wsm[9][32];
  int bx = blockIdx.x;
  int cq = bx >> 7;
  int rem = bx & 127;
  int bimg = rem >> 4, ys = rem & 15;
  int p = cq >> 2, q = cq & 3;
  int y0 = ys * 4;
  int tid = threadIdx.x, wv = tid >> 6, l = tid & 63;
  const unsigned short* h1p = p ? h1p123 + (size_t)(p - 1) * 4194304 : h1p0;
  unsigned short* h2p = p ? h2p123 + (size_t)(p - 1) * 4194304 : h2p0;
  size_t ibase = (size_t)bimg * 4096;
  for (int i = tid; i < 288; i += 256)
    wsm[0][i] = dwt[(size_t)p * 1152 + (i >> 5) * 128 + q * 32 + (i & 31)];
#pragma unroll
  for (int it = 0; it < 6; ++it) {
    int cb = it * 4 + wv;
    int row = cb >> 2, colblk = cb & 3;
    int yy = y0 - 1 + row;
    int ldsbase = (row * 64 + colblk * 16) * 64;
    if ((unsigned)yy < 64u) {
      const char* src = (const char*)h1p +
          (ibase + (size_t)yy * 64 + colblk * 16 + (l >> 2)) * 256 + q * 64 + (l & 3) * 16;
      gld16(src, (char*)HT + ldsbase);
    } else {
      *(uint4*)((char*)HT + ldsbase + l * 16) = make_uint4(0, 0, 0, 0);
    }
  }
  int grp = tid >> 2, c8q = tid & 3;
  int ch0 = p * 128 + q * 32 + c8q * 8;
  const float4 bs0 = *(const float4*)(dw_b + ch0);
  const float4 bs1 = *(const float4*)(dw_b + ch0 + 4);
  __syncthreads();

  int col = grp;
#pragma unroll
  for (int r = 0; r < 4; ++r) {
    float acw[8];
    acw[0] = bs0.x; acw[1] = bs0.y; acw[2] = bs0.z; acw[3] = bs0.w;
    acw[4] = bs1.x; acw[5] = bs1.y; acw[6] = bs1.z; acw[7] = bs1.w;
#pragma unroll
    for (int dy = 0; dy < 3; ++dy) {
#pragma unroll
      for (int dx = 0; dx < 3; ++dx) {
        int xc = col + dx - 1;
        if ((unsigned)xc < 64u) {
          const uint4 u = *(const uint4*)((const char*)HT +
              (((r + dy) * 64 + xc) * 64) + c8q * 16);
          const float4 wa  = *(const float4*)(&wsm[dy * 3 + dx][c8q * 8]);
          const float4 wb2 = *(const float4*)(&wsm[dy * 3 + dx][c8q * 8 + 4]);
          acw[0] += wa.x * bflo(u.x);  acw[1] += wa.y * bfhi(u.x);
          acw[2] += wa.z * bflo(u.y);  acw[3] += wa.w * bfhi(u.y);
          acw[4] += wb2.x * bflo(u.z); acw[5] += wb2.y * bfhi(u.z);
          acw[6] += wb2.z * bflo(u.w); acw[7] += wb2.w * bfhi(u.w);
        }
      }
    }
    size_t sidx = ibase + (size_t)(y0 + r) * 64 + col;
    int c16o = q * 4 + c8q;
    unsigned int o0 = (unsigned int)f2bf(gelu_f(acw[0])) | ((unsigned int)f2bf(gelu_f(acw[1])) << 16);
    unsigned int o1 = (unsigned int)f2bf(gelu_f(acw[2])) | ((unsigned int)f2bf(gelu_f(acw[3])) << 16);
    unsigned int o2 = (unsigned int)f2bf(gelu_f(acw[4])) | ((unsigned int)f2bf(gelu_f(acw[5])) << 16);
    unsigned int o3 = (unsigned int)f2bf(gelu_f(acw[6])) | ((unsigned int)f2bf(gelu_f(acw[7])) << 16);
    *(uint4*)(h2p + sidx * 128 + ((c16o ^ (int)(sidx & 7)) << 3)) = make_uint4(o0, o1, o2, o3);
  }
}

// ---------------- MFMA lin2 + residual(bf16) + bias ----------------
__global__ __launch_bounds__(256) void lin2_kernel(const unsigned short* __restrict__ h2p0,
    const unsigned short* __restrict__ h2p123, const unsigned short* __restrict__ wb,
    const float* __restrict__ bias, const unsigned short* __restrict__ xres,
    float* __restrict__ out) {
  __shared__ uint4 XA[1024];
  __shared__ uint4 XB[2048];
  size_t rb = (size_t)blockIdx.x * 64;
  int tid = threadIdx.x, wv = tid >> 6, l = tid & 63;
  const f32x4 zero = {0.f, 0.f, 0.f, 0.f};
  f32x4 acc[8];
#pragma unroll
  for (int nt = 0; nt < 8; ++nt) acc[nt] = zero;
  int r = wv * 16 + (l & 15);
  for (int kt = 0; kt < 4; ++kt) {
    if (kt) __syncthreads();
    const unsigned short* hp = (kt == 0) ? h2p0 : h2p123 + (size_t)(kt - 1) * 4194304;
    const char* ga = (const char*)hp + rb * 256;
    const char* gb = (const char*)wb + (size_t)kt * 32768;
    for (int i = wv; i < 16; i += 4) gld16(ga + (i << 10) + l * 16, (char*)XA + (i << 10));
    for (int i = wv; i < 32; i += 4) gld16(gb + (i << 10) + l * 16, (char*)XB + (i << 10));
    __syncthreads();
    bf16x8 af[4];
#pragma unroll
    for (int ks = 0; ks < 4; ++ks) {
      int c16 = ks * 4 + (l >> 4);
      af[ks] = *(const bf16x8*)((const char*)XA + r * 256 + ((c16 ^ (r & 7)) << 4));
    }
#pragma unroll
    for (int nt = 0; nt < 8; ++nt) {
      int n = nt * 16 + (l & 15);
      bf16x8 bq[4];
#pragma unroll
      for (int ks = 0; ks < 4; ++ks) {
        int c16 = ks * 4 + (l >> 4);
        bq[ks] = *(const bf16x8*)((const char*)XB + n * 256 + ((c16 ^ (n & 7)) << 4));
      }
#pragma unroll
      for (int ks = 0; ks < 4; ++ks)
        acc[nt] = __builtin_amdgcn_mfma_f32_16x16x32_bf16(af[ks], bq[ks], acc[nt], 0, 0, 0);
    }
  }
#pragma unroll
  for (int nt = 0; nt < 8; ++nt) {
    int n = nt * 16 + (l & 15);
    float bsv = bias[n];
#pragma unroll
    for (int r2 = 0; r2 < 4; ++r2) {
      size_t row = rb + wv * 16 + (l >> 4) * 4 + r2;
      size_t gi = row * NC + n;
      out[gi] = bf2f(xres[gi]) + acc[nt][r2] + bsv;
    }
  }
}

extern "C" void kernel_launch(void* const* d_in, const int* in_sizes, int n_in,
                              void* d_out, int out_size, void* d_ws, size_t ws_size,
                              hipStream_t stream) {
  (void)in_sizes; (void)n_in; (void)out_size; (void)ws_size;
  const float* x       = (const float*)d_in[0];
  const float* ln1_g   = (const float*)d_in[1];
  const float* ln1_b   = (const float*)d_in[2];
  const float* conv1_w = (const float*)d_in[3];
  const float* w_down  = (const float*)d_in[4];
  const float* b_down  = (const float*)d_in[5];
  const float* w1      = (const float*)d_in[6];
  const float* b1      = (const float*)d_in[7];
  const float* w2      = (const float*)d_in[8];
  const float* b2      = (const float*)d_in[9];
  const float* w_gk    = (const float*)d_in[10];
  const float* b_gk    = (const float*)d_in[11];
  const float* w_fus   = (const float*)d_in[12];
  const float* b_fus   = (const float*)d_in[13];
  const float* ln2_g   = (const float*)d_in[14];
  const float* ln2_b   = (const float*)d_in[15];
  const float* lin1_w  = (const float*)d_in[16];
  const float* lin1_b  = (const float*)d_in[17];
  const float* dw_w    = (const float*)d_in[18];
  const float* dw_b    = (const float*)d_in[19];
  const float* lin2_w  = (const float*)d_in[20];
  const float* lin2_b  = (const float*)d_in[21];
  float* out = (float*)d_out;
  char* ws = (char*)d_ws;

  unsigned short* xatt_bf = (unsigned short*)(ws);           // 8,388,608 (bf16)
  float*          Tb      = (float*)(ws + 16777216);         // 147,456
  float*          wgtb    = (float*)(ws + 16924672);         // 512
  float*          sfus    = (float*)(ws + 16925184);         // 512
  float*          dwt     = (float*)(ws + 16925696);         // 18,432
  unsigned short* Wgk_bf  = (unsigned short*)(ws + 16944128);// 131,072
  unsigned short* Wf1_bf  = (unsigned short*)(ws + 17075200);// 131,072
  unsigned short* Wf2_bf  = (unsigned short*)(ws + 17206272);// 32,768
  unsigned short* w1_bf   = (unsigned short*)(ws + 17239040);// 131,072
  unsigned short* w2_bf   = (unsigned short*)(ws + 17370112);// 131,072
  unsigned short* M_bf    = (unsigned short*)(ws + 17501184);// 2,359,296
  unsigned short* xln_bf  = (unsigned short*)(ws + 19860480);// 8,388,608 (reused as h1 plane0)
  unsigned short* xln2_bf = (unsigned short*)(ws + 28249088);// 8,388,608 (early: scratch; conv LN2 out; later h2 plane0)
  unsigned short* h1p123  = (unsigned short*)(ws + 36637696);// 25,165,824
  unsigned short* h2p123  = (unsigned short*)(ws + 61803520);// 25,165,824
  char* sc = ws + 28249088;
  float*          RSb     = (float*)(sc);                    // 524,288
  float*          Ub      = (float*)(sc + 524288);           // 18,432
  unsigned short* CTP_bf  = (unsigned short*)(sc + 542720);  // 1,179,648
  unsigned short* CTQ_bf  = (unsigned short*)(sc + 1722368); // 1,179,648
  unsigned short* G_bf    = (unsigned short*)(sc + 2902016); // 1,179,648
  float*          AWb     = (float*)(sc + 4081664);          // 2,359,296

  head_kernel<<<8603, 256, 0, stream>>>(x, ln1_g, ln1_b, xln_bf,
                                        lin1_w, lin2_w, w_gk, w_fus, dw_w, conv1_w,
                                        w1_bf, w2_bf, Wgk_bf, Wf1_bf, Wf2_bf, dwt, sfus,
                                        CTP_bf, CTQ_bf);
  rs_kernel<<<1024, 128, 0, stream>>>(xln_bf, RSb);
  gemmGT_kernel<<<68, 256, 0, stream>>>(Wgk_bf, CTP_bf, w_down, G_bf, Ub,
                                        xln_bf, RSb, Tb);
  gemmAWse_kernel<<<37, 256, 0, stream>>>(Wf1_bf, CTQ_bf, Wf2_bf, G_bf, AWb,
                                          Tb, Ub, b_down, w1, b1, w2, b2, wgtb);
  m_kernel<<<1024, 128, 0, stream>>>(AWb, wgtb, sfus, b_gk, M_bf);
  conv_kernel<<<512, 256, 0, stream>>>(x, xln_bf, M_bf, b_fus, ln2_g, ln2_b, xatt_bf, xln2_bf);
  lin1_kernel<<<512, 256, 0, stream>>>(xln2_bf, w1_bf, lin1_b, xln_bf /*h1 p0*/, h1p123);
  dw_kernel<<<2048, 256, 0, stream>>>(xln_bf /*h1 p0*/, h1p123, dwt, dw_b,
                                      xln2_bf /*h2 p0*/, h2p123);
  lin2_kernel<<<512, 256, 0, stream>>>(xln2_bf /*h2 p0*/, h2p123, w2_bf, lin2_b, xatt_bf, out);
}